// Round 2
// baseline (37.501 us; speedup 1.0000x reference)
//
#include <hip/hip_runtime.h>
#include <hip/hip_bf16.h>

// CSPN step: out[b,y,x] = sum_{i,j} gw[b, i*3+j, y+1, x+1] * src[y+1-i, x+1-j]
// src = h0 for center tap (i=j=1), hn otherwise; zero outside [0,H)x[0,W).
// 4 pixels per thread along x; fast branch-free interior path.

constexpr int B = 8;
constexpr int H = 352;
constexpr int W = 1216;
constexpr int HP = H + 2;            // 354
constexpr int WP = W + 2;            // 1218
constexpr int CPR = W / 4;           // x-chunks per row = 304
constexpr size_t PLANE = (size_t)HP * WP;

typedef float f2 __attribute__((ext_vector_type(2)));
typedef float f4 __attribute__((ext_vector_type(4)));

__global__ __launch_bounds__(256) void cspn4_kernel(
    const float* __restrict__ gw,   // [B, 9, HP, WP]
    const float* __restrict__ hn,   // [B, 1, H, W]
    const float* __restrict__ h0,   // [B, 1, H, W]
    float* __restrict__ out)        // [B, 1, H, W]
{
    int tid = blockIdx.x * blockDim.x + threadIdx.x;
    int cx = tid % CPR;
    int t2 = tid / CPR;
    int y  = t2 % H;
    int b  = t2 / H;
    int x0 = cx * 4;

    // gw pointer at tap 0, col (x0+1): odd element offset -> gt+1 is 8B aligned
    const float* gwp = gw + (size_t)b * 9 * PLANE + (size_t)(y + 1) * WP + (x0 + 1);
    const float* hnb = hn + (size_t)b * H * W;
    const float* h0b = h0 + (size_t)b * H * W;
    const float* h0p = h0b + (size_t)y * W + x0;
    float* outp = out + (size_t)b * H * W + (size_t)y * W + x0;

    float acc0 = 0.f, acc1 = 0.f, acc2 = 0.f, acc3 = 0.f;

    bool interior = (y >= 1) & (y <= H - 2) & (cx >= 1) & (cx <= CPR - 2);
    if (interior) {
        // hn rows: r[i] is row yy = y+1-i, cols x0-1 .. x0+4
        float r[3][6];
#pragma unroll
        for (int i = 0; i < 3; ++i) {
            const float* rp = hnb + (size_t)(y + 1 - i) * W + x0;
            r[i][0] = rp[-1];
            f4 v = *reinterpret_cast<const f4*>(rp);   // 16B aligned
            r[i][1] = v[0]; r[i][2] = v[1]; r[i][3] = v[2]; r[i][4] = v[3];
            r[i][5] = rp[4];
        }
        f4 c = *reinterpret_cast<const f4*>(h0p);      // center tap source

#pragma unroll
        for (int i = 0; i < 3; ++i) {
#pragma unroll
            for (int j = 0; j < 3; ++j) {
                const int t = i * 3 + j;
                const float* gt = gwp + (size_t)t * PLANE;
                float g0 = __builtin_nontemporal_load(gt);
                f2 g12 = __builtin_nontemporal_load(reinterpret_cast<const f2*>(gt + 1));
                float g3 = __builtin_nontemporal_load(gt + 3);
                if (t == 4) {
                    acc0 = fmaf(g0,     c[0], acc0);
                    acc1 = fmaf(g12[0], c[1], acc1);
                    acc2 = fmaf(g12[1], c[2], acc2);
                    acc3 = fmaf(g3,     c[3], acc3);
                } else {
                    // pixel p reads r[i][p + 2 - j]
                    acc0 = fmaf(g0,     r[i][2 - j], acc0);
                    acc1 = fmaf(g12[0], r[i][3 - j], acc1);
                    acc2 = fmaf(g12[1], r[i][4 - j], acc2);
                    acc3 = fmaf(g3,     r[i][5 - j], acc3);
                }
            }
        }
    } else {
        // Boundary path: per-pixel scalar with bounds checks.
        float acc[4] = {0.f, 0.f, 0.f, 0.f};
#pragma unroll
        for (int p = 0; p < 4; ++p) {
            int x = x0 + p;
#pragma unroll
            for (int i = 0; i < 3; ++i) {
                int yy = y + 1 - i;
                bool yin = (yy >= 0) & (yy < H);
#pragma unroll
                for (int j = 0; j < 3; ++j) {
                    const int t = i * 3 + j;
                    int xx = x + 1 - j;
                    bool in = yin & (xx >= 0) & (xx < W);
                    float s = 0.f;
                    if (in) {
                        const float* src = (t == 4) ? h0b : hnb;
                        s = src[(size_t)yy * W + xx];
                    }
                    acc[p] = fmaf(gwp[(size_t)t * PLANE + p], s, acc[p]);
                }
            }
        }
        acc0 = acc[0]; acc1 = acc[1]; acc2 = acc[2]; acc3 = acc[3];
    }

    f4 o; o[0] = acc0; o[1] = acc1; o[2] = acc2; o[3] = acc3;
    __builtin_nontemporal_store(o, reinterpret_cast<f4*>(outp));
}

extern "C" void kernel_launch(void* const* d_in, const int* in_sizes, int n_in,
                              void* d_out, int out_size, void* d_ws, size_t ws_size,
                              hipStream_t stream) {
    const float* gw = (const float*)d_in[0];
    const float* hn = (const float*)d_in[1];
    const float* h0 = (const float*)d_in[2];
    float* out = (float*)d_out;

    constexpr int total = B * H * CPR;       // 856064 threads, 4 px each
    constexpr int block = 256;
    constexpr int grid = total / block;      // 3344 exact
    cspn4_kernel<<<grid, block, 0, stream>>>(gw, hn, h0, out);
}